// Round 14
// baseline (365.944 us; speedup 1.0000x reference)
//
#include <hip/hip_runtime.h>

typedef __bf16 bf16;
typedef bf16 bf16x8 __attribute__((ext_vector_type(8)));
typedef bf16 bf16x4 __attribute__((ext_vector_type(4)));
typedef float floatx4 __attribute__((ext_vector_type(4)));

#define D_MODEL 1024
#define SEQ     2048
#define NB      4
#define NH      16
#define DKH     64
// log2(10000)/32
#define ROPE_L2 0.4152410118609203f

__device__ __forceinline__ floatx4 mfma16(bf16x8 a, bf16x8 b, floatx4 c) {
  return __builtin_amdgcn_mfma_f32_16x16x32_bf16(a, b, c, 0, 0, 0);
}

// Async global->LDS, 16B per lane. lds base must be wave-uniform; HW adds lane*16.
__device__ __forceinline__ void gload_lds16(void* lds_uniform, const void* gsrc) {
  __builtin_amdgcn_global_load_lds(
      (__attribute__((address_space(1))) unsigned int*)(void*)(gsrc),
      (__attribute__((address_space(3))) unsigned int*)lds_uniform,
      16, 0, 0);
}

// ---------------- fused fp32 -> bf16 conversion (x + 4 weights, ONE launch) ----------------
__global__ __launch_bounds__(256) void cvt_all(
    const float4* __restrict__ x,
    const float4* __restrict__ wq, const float4* __restrict__ wk,
    const float4* __restrict__ wv, const float4* __restrict__ wo,
    bf16x4* __restrict__ xb,
    bf16x4* __restrict__ b0, bf16x4* __restrict__ b1,
    bf16x4* __restrict__ b2, bf16x4* __restrict__ b3) {
  const int i = blockIdx.x * 256 + threadIdx.x;
  const float4* src;
  bf16x4* dst;
  int off;
  if (i < (1 << 21)) {
    src = x; dst = xb; off = i;
  } else {
    const int j = i - (1 << 21);
    const int widx = j >> 18;
    off = j & ((1 << 18) - 1);
    src = (widx == 0) ? wq : (widx == 1) ? wk : (widx == 2) ? wv : wo;
    dst = (widx == 0) ? b0 : (widx == 1) ? b1 : (widx == 2) ? b2 : b3;
  }
  const float4 v = src[off];
  bf16x4 o;
  o[0] = (bf16)v.x; o[1] = (bf16)v.y; o[2] = (bf16)v.z; o[3] = (bf16)v.w;
  dst[off] = o;
}

// ---------------- RoPE sin/cos table: tab[s][i2] = {sin,cos}(pos[s]*theta^-i2) ----------------
__global__ __launch_bounds__(256) void rope_table(const int* __restrict__ tokpos,
                                                  float2* __restrict__ tab) {
  const int i = blockIdx.x * 256 + threadIdx.x;  // [0, 2048*32)
  const int s = i >> 5, i2 = i & 31;
  const float ang = (float)tokpos[s] * exp2f(-(float)i2 * ROPE_L2);
  float sn, cs;
  sincosf(ang, &sn, &cs);
  tab[i] = make_float2(sn, cs);
}

// ---------------- DIRECT-FROM-L2 GEMM core: C(128x128) = A @ W^T, K=1024 ----------------
// R14: NO LDS, NO barriers. R12 arithmetic: the 2-phase LDS structure moves
// ~48KB/K-step through the LDS pipe (~480cy) vs 78cy MFMA -> MfmaUtil ~20%
// regardless of dbuf (R9), occupancy (R11), L2 locality (R12), or counted
// vmcnt (R13, regressed: T4 needs 8-phase). Per-K-step working set is 8KB A +
// 8KB B (L1/L2-hot; B is 2MB = L2-resident per XCD after R12 chunking), so
// stage NOTHING (Common-mistake #7): each wave reads MFMA fragments directly
// from global with the exact same 16B/lane layout. 2-deep register ping-pong;
// 12 waves/CU slip freely with zero sync points.
#define GEMM_ACC_DECL                              \
  floatx4 c00 = {}, c01 = {}, c02 = {}, c03 = {};  \
  floatx4 c10 = {}, c11 = {}, c12 = {}, c13 = {};  \
  floatx4 c20 = {}, c21 = {}, c22 = {}, c23 = {};  \
  floatx4 c30 = {}, c31 = {}, c32 = {}, c33 = {};

#define DG_DECL_PTRS(Aptr, Bptr)                                                  \
  const bf16* pa0 = (Aptr) + (size_t)(bm + wr * 64 +  0 + r) * D_MODEL + g * 8;   \
  const bf16* pa1 = (Aptr) + (size_t)(bm + wr * 64 + 16 + r) * D_MODEL + g * 8;   \
  const bf16* pa2 = (Aptr) + (size_t)(bm + wr * 64 + 32 + r) * D_MODEL + g * 8;   \
  const bf16* pa3 = (Aptr) + (size_t)(bm + wr * 64 + 48 + r) * D_MODEL + g * 8;   \
  const bf16* pb0 = (Bptr) + (size_t)(bn + wc * 64 +  0 + r) * D_MODEL + g * 8;   \
  const bf16* pb1 = (Bptr) + (size_t)(bn + wc * 64 + 16 + r) * D_MODEL + g * 8;   \
  const bf16* pb2 = (Bptr) + (size_t)(bn + wc * 64 + 32 + r) * D_MODEL + g * 8;   \
  const bf16* pb3 = (Bptr) + (size_t)(bn + wc * 64 + 48 + r) * D_MODEL + g * 8;

#define DG_LOAD(SET, K)                                                        \
  SET##a0 = *(const bf16x8*)(pa0 + (size_t)(K) * 32);                          \
  SET##a1 = *(const bf16x8*)(pa1 + (size_t)(K) * 32);                          \
  SET##a2 = *(const bf16x8*)(pa2 + (size_t)(K) * 32);                          \
  SET##a3 = *(const bf16x8*)(pa3 + (size_t)(K) * 32);                          \
  SET##b0 = *(const bf16x8*)(pb0 + (size_t)(K) * 32);                          \
  SET##b1 = *(const bf16x8*)(pb1 + (size_t)(K) * 32);                          \
  SET##b2 = *(const bf16x8*)(pb2 + (size_t)(K) * 32);                          \
  SET##b3 = *(const bf16x8*)(pb3 + (size_t)(K) * 32);

#define DG_COMPUTE(SET)                                                        \
  __builtin_amdgcn_s_setprio(1);                                               \
  c00 = mfma16(SET##a0, SET##b0, c00); c01 = mfma16(SET##a0, SET##b1, c01);    \
  c02 = mfma16(SET##a0, SET##b2, c02); c03 = mfma16(SET##a0, SET##b3, c03);    \
  c10 = mfma16(SET##a1, SET##b0, c10); c11 = mfma16(SET##a1, SET##b1, c11);    \
  c12 = mfma16(SET##a1, SET##b2, c12); c13 = mfma16(SET##a1, SET##b3, c13);    \
  c20 = mfma16(SET##a2, SET##b0, c20); c21 = mfma16(SET##a2, SET##b1, c21);    \
  c22 = mfma16(SET##a2, SET##b2, c22); c23 = mfma16(SET##a2, SET##b3, c23);    \
  c30 = mfma16(SET##a3, SET##b0, c30); c31 = mfma16(SET##a3, SET##b1, c31);    \
  c32 = mfma16(SET##a3, SET##b2, c32); c33 = mfma16(SET##a3, SET##b3, c33);    \
  __builtin_amdgcn_s_setprio(0);

// iter kt: COMPUTE(s0=k_kt) | LOAD(s0<-kt+2) | COMPUTE(s1=k_kt+1) | LOAD(s1<-kt+3)
// each set's loads are ~2 MFMA-clusters (~160-200cy) old at use. Tail peeled.
#define GEMM_MAINLOOP(Aptr, Bptr)                                              \
  DG_DECL_PTRS(Aptr, Bptr)                                                     \
  bf16x8 s0a0, s0a1, s0a2, s0a3, s0b0, s0b1, s0b2, s0b3;                       \
  bf16x8 s1a0, s1a1, s1a2, s1a3, s1b0, s1b1, s1b2, s1b3;                       \
  DG_LOAD(s0, 0)                                                               \
  DG_LOAD(s1, 1)                                                               \
  _Pragma("unroll 1")                                                          \
  for (int kt = 0; kt < 30; kt += 2) {                                         \
    DG_COMPUTE(s0)                                                             \
    DG_LOAD(s0, kt + 2)                                                        \
    DG_COMPUTE(s1)                                                             \
    DG_LOAD(s1, kt + 3)                                                        \
  }                                                                            \
  DG_COMPUTE(s0)                                                               \
  DG_COMPUTE(s1)

// ---------------- QKV projection, RoPE (table) fused, layout transform ----------------
// Q is pre-scaled by 1/sqrt(dk)=0.125 (power of 2 -> exact in bf16).
#define QKV_EPI(mm, nn, CV)                                                    \
  _Pragma("unroll")                                                            \
  for (int reg = 0; reg < 4; ++reg) {                                          \
    const int grow = bm + wr * 64 + mm * 16 + g * 4 + reg;                     \
    const int gcol = bn + wc * 64 + nn * 16 + r;                               \
    const int b_ = grow >> 11, s_ = grow & (SEQ - 1);                          \
    const int h_ = gcol >> 6, d_ = gcol & 63;                                  \
    float v = CV[reg];                                                         \
    if (z < 2) {                                                               \
      float p = __shfl_xor(v, 1);                                              \
      const float2 sc2 = ropetab[s_ * 32 + (d_ >> 1)];                         \
      float res = ((d_ & 1) == 0) ? (sc2.y * v - sc2.x * p)                    \
                                  : (sc2.x * p + sc2.y * v);                   \
      if (z == 0) res *= 0.125f;                                               \
      bf16* dst = (z == 0) ? Qd : Kd;                                          \
      dst[(((size_t)(b_ * NH + h_)) * SEQ + s_) * DKH + d_] = (bf16)res;       \
    } else {                                                                   \
      Vd[(((size_t)(b_ * NH + h_)) * DKH + d_) * SEQ + s_] = (bf16)v;          \
    }                                                                          \
  }

// grid (8, 64, 3) = 1536 blocks. XCD-chunked: l = (orig%8)*192 + orig/8.
__global__ __launch_bounds__(256, 3) void gemm_qkv(
    const bf16* __restrict__ A,
    const bf16* __restrict__ W0, const bf16* __restrict__ W1, const bf16* __restrict__ W2,
    bf16* __restrict__ Qd, bf16* __restrict__ Kd, bf16* __restrict__ Vd,
    const float2* __restrict__ ropetab) {
  const int orig = (int)(blockIdx.x + (blockIdx.y << 3) + (blockIdx.z << 9));
  const int l = (orig & 7) * 192 + (orig >> 3);
  const int z = l >> 9;
  const int bm = ((l >> 3) & 63) * 128, bn = (l & 7) * 128;
  const bf16* Bw = (z == 0) ? W0 : (z == 1) ? W1 : W2;
  const int tid = threadIdx.x, lane = tid & 63, w = tid >> 6;
  const int wr = w >> 1, wc = w & 1;
  const int r = lane & 15, g = lane >> 4;
  GEMM_ACC_DECL
  GEMM_MAINLOOP(A, Bw)

  QKV_EPI(0, 0, c00) QKV_EPI(0, 1, c01) QKV_EPI(0, 2, c02) QKV_EPI(0, 3, c03)
  QKV_EPI(1, 0, c10) QKV_EPI(1, 1, c11) QKV_EPI(1, 2, c12) QKV_EPI(1, 3, c13)
  QKV_EPI(2, 0, c20) QKV_EPI(2, 1, c21) QKV_EPI(2, 2, c22) QKV_EPI(2, 3, c23)
  QKV_EPI(3, 0, c30) QKV_EPI(3, 1, c31) QKV_EPI(3, 2, c32) QKV_EPI(3, 3, c33)
}

// ---------------- output projection: d_out = AO @ Wo^T (fp32 row-major) ----------------
#define OUT_EPI(mm, nn, CV)                                                    \
  _Pragma("unroll")                                                            \
  for (int reg = 0; reg < 4; ++reg) {                                          \
    const int grow = bm + wr * 64 + mm * 16 + g * 4 + reg;                     \
    const int gcol = bn + wc * 64 + nn * 16 + r;                               \
    C[(size_t)grow * D_MODEL + gcol] = CV[reg];                                \
  }

// grid (8, 64) = 512 blocks; chunked swizzle with q = 64.
__global__ __launch_bounds__(256, 3) void gemm_out(const bf16* __restrict__ A,
                                                   const bf16* __restrict__ Bw,
                                                   float* __restrict__ C) {
  const int orig = (int)(blockIdx.x + (blockIdx.y << 3));
  const int l = (orig & 7) * 64 + (orig >> 3);
  const int bm = (l >> 3) * 128, bn = (l & 7) * 128;
  const int tid = threadIdx.x, lane = tid & 63, w = tid >> 6;
  const int wr = w >> 1, wc = w & 1;
  const int r = lane & 15, g = lane >> 4;
  GEMM_ACC_DECL
  GEMM_MAINLOOP(A, Bw)
  OUT_EPI(0, 0, c00) OUT_EPI(0, 1, c01) OUT_EPI(0, 2, c02) OUT_EPI(0, 3, c03)
  OUT_EPI(1, 0, c10) OUT_EPI(1, 1, c11) OUT_EPI(1, 2, c12) OUT_EPI(1, 3, c13)
  OUT_EPI(2, 0, c20) OUT_EPI(2, 1, c21) OUT_EPI(2, 2, c22) OUT_EPI(2, 3, c23)
  OUT_EPI(3, 0, c30) OUT_EPI(3, 1, c31) OUT_EPI(3, 2, c32) OUT_EPI(3, 3, c33)
}

// ---------------- causal flash attention, triangle-paired blocks ----------------
// grid (8, 64) = 512 blocks, XCD-chunked. Block bx handles q-tiles {bx, 15-bx}
// = exactly 34 K/V-tiles each. Fixed-max softmax (M=12), per-lane deferred
// row-sums, Q pre-scaled 1/8, setprio around MFMA. (R12 state, unchanged.)
__global__ __launch_bounds__(256, 2) void attn128(const bf16* __restrict__ Q,
                                                  const bf16* __restrict__ Kk,
                                                  const bf16* __restrict__ Vt,
                                                  bf16* __restrict__ AO) {
  const int orig = (int)(blockIdx.x + (blockIdx.y << 3));
  const int l = (orig & 7) * 64 + (orig >> 3);
  const int bx = l & 7;
  const int bh = l >> 3;
  const int b = bh >> 4, h = bh & 15;
  const int tid = threadIdx.x, lane = tid & 63, w = tid >> 6;
  const int r = lane & 15, g = lane >> 4;

  const bf16* Qb = Q + (size_t)bh * SEQ * DKH;
  const bf16* Kb = Kk + (size_t)bh * SEQ * DKH;
  const bf16* Vb = Vt + (size_t)bh * DKH * SEQ;

  __shared__ bf16 Ks[2][64 * 64];  // [token][d], XOR-swizzled
  __shared__ bf16 Vs[2][64 * 64];  // [d][token], XOR-swizzled
  __shared__ bf16 Ps[4][32 * 64];  // per-wave P, XOR-swizzled

  // staging constants: linear LDS byte L -> pre-swizzled global source
  int ldsoff[2];
  const char* ksrc[2];
  const char* vsrc[2];
#pragma unroll
  for (int j = 0; j < 2; ++j) {
    const int L = (w * 64 + lane + 256 * j) * 16;
    const int S = L ^ (((L >> 7) & 7) << 4);
    ldsoff[j] = (w * 64 + 256 * j) * 16;
    ksrc[j] = (const char*)Kb + S;
    vsrc[j] = (const char*)Vb + (size_t)(S >> 7) * (SEQ * 2) + (S & 127);
  }

// K tile stride = 64 tok * 64 d * 2B = 8192 B; V tile stride = 64 tok * 2B = 128 B.
#define ATTN_STAGE(buf, tt)                                                   \
  _Pragma("unroll")                                                           \
  for (int j = 0; j < 2; ++j) {                                               \
    gload_lds16((char*)Ks[buf] + ldsoff[j], ksrc[j] + (size_t)(tt) * 8192);   \
    gload_lds16((char*)Vs[buf] + ldsoff[j], vsrc[j] + (size_t)(tt) * 128);    \
  }

// softmax tile body: p = exp2(fma(s, log2e, -12*log2e)); optional causal mask;
// accumulate l2; write bf16 p to swizzled Ps.
#define SM_TILE(MASKED)                                                        \
  _Pragma("unroll")                                                            \
  for (int m = 0; m < 2; ++m) {                                                \
    _Pragma("unroll")                                                          \
    for (int nf = 0; nf < 4; ++nf) {                                           \
      floatx4 p;                                                               \
      _Pragma("unroll")                                                        \
      for (int reg = 0; reg < 4; ++reg) {                                      \
        float pe = exp2f(fmaf(sc[m][nf][reg], 1.442695041f, -17.31234049f));   \
        if (MASKED && (t0 + nf * 16 + r > q0 + m * 16 + g * 4 + reg))          \
          pe = 0.f;                                                            \
        p[reg] = pe;                                                           \
      }                                                                        \
      l2[m] += p;                                                              \
      _Pragma("unroll")                                                        \
      for (int reg = 0; reg < 4; ++reg) {                                      \
        const int wl = m * 16 + g * 4 + reg;                                   \
        const int pb = (wl * 128 + (nf * 16 + r) * 2) ^ ((wl & 7) << 4);       \
        *(bf16*)((char*)Ps[w] + pb) = (bf16)p[reg];                            \
      }                                                                        \
    }                                                                          \
  }

  for (int half = 0; half < 2; ++half) {
    const int qt = half ? (15 - bx) : bx;
    const int q0 = qt * 128 + w * 32;

    // Q fragments: qf[m][ks], rows q0 + m*16 + r
    bf16x8 qf[2][2];
#pragma unroll
    for (int m = 0; m < 2; ++m)
#pragma unroll
      for (int ks = 0; ks < 2; ++ks)
        qf[m][ks] = *(const bf16x8*)(Qb + (size_t)(q0 + m * 16 + r) * DKH + ks * 32 + g * 8);

    floatx4 o[2][4] = {};
    floatx4 l2[2] = {};  // per-lane partial row-sums, reduced after the loop

    const int nt = 2 * qt + 2;
    ATTN_STAGE(0, 0)
    __syncthreads();
    int cu = 0;
    for (int t = 0; t < nt; ++t) {
      if (t + 1 < nt) ATTN_STAGE(cu ^ 1, t + 1)
      const int t0 = t * 64;

      // scores = Q @ K^T  (32 q-rows x 64 tokens), pre-scaled via Q
      floatx4 sc[2][4];
      __builtin_amdgcn_s_setprio(1);
#pragma unroll
      for (int nf = 0; nf < 4; ++nf) {
        const int row = nf * 16 + r;
        const int off0 = (row * 128 + g * 16) ^ ((row & 7) << 4);
        bf16x8 kf0 = *(const bf16x8*)((const char*)Ks[cu] + off0);
        bf16x8 kf1 = *(const bf16x8*)((const char*)Ks[cu] + (off0 ^ 64));
        sc[0][nf] = mfma16(qf[0][1], kf1, mfma16(qf[0][0], kf0, floatx4{0.f, 0.f, 0.f, 0.f}));
        sc[1][nf] = mfma16(qf[1][1], kf1, mfma16(qf[1][0], kf0, floatx4{0.f, 0.f, 0.f, 0.f}));
      }
      __builtin_amdgcn_s_setprio(0);

      const bool edge = (t0 + 63 > q0);  // wave-uniform branch
      if (edge) {
        SM_TILE(1)
      } else {
        SM_TILE(0)
      }
      // make this wave's P writes visible to its own ds_reads
      asm volatile("s_waitcnt lgkmcnt(0)" ::: "memory");

      // O += P @ V
      bf16x8 pf[2][2];
#pragma unroll
      for (int m = 0; m < 2; ++m)
#pragma unroll
        for (int ks = 0; ks < 2; ++ks) {
          const int prow = m * 16 + r;
          const int ab = (prow * 128 + ks * 64 + g * 16) ^ ((prow & 7) << 4);
          pf[m][ks] = *(const bf16x8*)((const char*)Ps[w] + ab);
        }
      __builtin_amdgcn_s_setprio(1);
#pragma unroll
      for (int nf = 0; nf < 4; ++nf) {
        const int vrow = nf * 16 + r;
        const int vb0 = (vrow * 128 + g * 16) ^ ((vrow & 7) << 4);
        bf16x8 vf0 = *(const bf16x8*)((const char*)Vs[cu] + vb0);
        bf16x8 vf1 = *(const bf16x8*)((const char*)Vs[cu] + (vb0 ^ 64));
#pragma unroll
        for (int m = 0; m < 2; ++m)
          o[m][nf] = mfma16(pf[m][1], vf1, mfma16(pf[m][0], vf0, o[m][nf]));
      }
      __builtin_amdgcn_s_setprio(0);
      __syncthreads();  // drains vmcnt (t+1 staged) + all reads of buffer cu done
      cu ^= 1;
    }

    // one-time row-sum reduction over the 16 r-lanes, then finalize
    float linv[2][4];
#pragma unroll
    for (int m = 0; m < 2; ++m)
#pragma unroll
      for (int reg = 0; reg < 4; ++reg) {
        float sum = l2[m][reg];
#pragma unroll
        for (int off = 1; off < 16; off <<= 1) sum += __shfl_xor(sum, off);
        linv[m][reg] = 1.f / sum;
      }

#pragma unroll
    for (int m = 0; m < 2; ++m)
#pragma unroll
      for (int nf = 0; nf < 4; ++nf)
#pragma unroll
        for (int reg = 0; reg < 4; ++reg) {
          const int s = q0 + m * 16 + g * 4 + reg;
          const int d = nf * 16 + r;
          const float val = o[m][nf][reg] * linv[m][reg];
          AO[((size_t)(b * SEQ + s)) * D_MODEL + h * DKH + d] = (bf16)val;
        }
    // last t-iteration's __syncthreads guarantees no wave still reads LDS;
    // epilogue touches no LDS, so half 1 may restage immediately.
  }
}

// ---------------- launcher ----------------
extern "C" void kernel_launch(void* const* d_in, const int* in_sizes, int n_in,
                              void* d_out, int out_size, void* d_ws, size_t ws_size,
                              hipStream_t stream) {
  const float* x = (const float*)d_in[0];
  const int* tokpos = (const int*)d_in[1];
  const float* Wq = (const float*)d_in[2];
  const float* Wk = (const float*)d_in[3];
  const float* Wv = (const float*)d_in[4];
  const float* Wo = (const float*)d_in[5];
  float* out = (float*)d_out;

  char* ws = (char*)d_ws;
  if (ws_size < (72ull << 20)) return;  // need 72 MiB scratch

  bf16* xb  = (bf16*)(ws);                     // 16 MiB [8192,1024]
  bf16* wb0 = (bf16*)(ws + (16ull << 20));     // 2 MiB each
  bf16* wb1 = (bf16*)(ws + (18ull << 20));
  bf16* wb2 = (bf16*)(ws + (20ull << 20));
  bf16* wb3 = (bf16*)(ws + (22ull << 20));
  bf16* Qb  = (bf16*)(ws + (24ull << 20));     // 16 MiB [B,H,S,64]
  bf16* Kb  = (bf16*)(ws + (40ull << 20));     // 16 MiB
  bf16* Vt  = (bf16*)(ws + (56ull << 20));     // 16 MiB [B,H,64,S]
  bf16* AO  = (bf16*)(ws);                     // reuse xb region (dead after QKV)
  // RoPE table lives in d_out's head (512 KB); consumed by gemm_qkv, then d_out
  // is fully overwritten by gemm_out afterwards (stream-ordered, deterministic).
  float2* ropetab = (float2*)d_out;

  rope_table<<<256, 256, 0, stream>>>(tokpos, ropetab);
  cvt_all<<<12288, 256, 0, stream>>>((const float4*)x, (const float4*)Wq,
                                     (const float4*)Wk, (const float4*)Wv,
                                     (const float4*)Wo, (bf16x4*)xb,
                                     (bf16x4*)wb0, (bf16x4*)wb1,
                                     (bf16x4*)wb2, (bf16x4*)wb3);

  gemm_qkv<<<dim3(8, 64, 3), 256, 0, stream>>>(xb, wb0, wb1, wb2, Qb, Kb, Vt, ropetab);
  attn128<<<dim3(8, 64), 256, 0, stream>>>(Qb, Kb, Vt, AO);
  gemm_out<<<dim3(8, 64), 256, 0, stream>>>(AO, wb3, out);
}

// Round 15
// 192.848 us; speedup vs baseline: 1.8976x; 1.8976x over previous
//
#include <hip/hip_runtime.h>

typedef __bf16 bf16;
typedef bf16 bf16x8 __attribute__((ext_vector_type(8)));
typedef bf16 bf16x4 __attribute__((ext_vector_type(4)));
typedef float floatx4 __attribute__((ext_vector_type(4)));

#define D_MODEL 1024
#define SEQ     2048
#define NB      4
#define NH      16
#define DKH     64
// log2(10000)/32
#define ROPE_L2 0.4152410118609203f

__device__ __forceinline__ floatx4 mfma16(bf16x8 a, bf16x8 b, floatx4 c) {
  return __builtin_amdgcn_mfma_f32_16x16x32_bf16(a, b, c, 0, 0, 0);
}

// Async global->LDS, 16B per lane. lds base must be wave-uniform; HW adds lane*16.
__device__ __forceinline__ void gload_lds16(void* lds_uniform, const void* gsrc) {
  __builtin_amdgcn_global_load_lds(
      (__attribute__((address_space(1))) unsigned int*)(void*)(gsrc),
      (__attribute__((address_space(3))) unsigned int*)lds_uniform,
      16, 0, 0);
}

// ---------------- fused fp32 -> bf16 conversion (x + 4 weights, ONE launch) ----------------
__global__ __launch_bounds__(256) void cvt_all(
    const float4* __restrict__ x,
    const float4* __restrict__ wq, const float4* __restrict__ wk,
    const float4* __restrict__ wv, const float4* __restrict__ wo,
    bf16x4* __restrict__ xb,
    bf16x4* __restrict__ b0, bf16x4* __restrict__ b1,
    bf16x4* __restrict__ b2, bf16x4* __restrict__ b3) {
  const int i = blockIdx.x * 256 + threadIdx.x;
  const float4* src;
  bf16x4* dst;
  int off;
  if (i < (1 << 21)) {
    src = x; dst = xb; off = i;
  } else {
    const int j = i - (1 << 21);
    const int widx = j >> 18;
    off = j & ((1 << 18) - 1);
    src = (widx == 0) ? wq : (widx == 1) ? wk : (widx == 2) ? wv : wo;
    dst = (widx == 0) ? b0 : (widx == 1) ? b1 : (widx == 2) ? b2 : b3;
  }
  const float4 v = src[off];
  bf16x4 o;
  o[0] = (bf16)v.x; o[1] = (bf16)v.y; o[2] = (bf16)v.z; o[3] = (bf16)v.w;
  dst[off] = o;
}

// ---------------- RoPE sin/cos table: tab[s][i2] = {sin,cos}(pos[s]*theta^-i2) ----------------
__global__ __launch_bounds__(256) void rope_table(const int* __restrict__ tokpos,
                                                  float2* __restrict__ tab) {
  const int i = blockIdx.x * 256 + threadIdx.x;  // [0, 2048*32)
  const int s = i >> 5, i2 = i & 31;
  const float ang = (float)tokpos[s] * exp2f(-(float)i2 * ROPE_L2);
  float sn, cs;
  sincosf(ang, &sn, &cs);
  tab[i] = make_float2(sn, cs);
}

// ---------------- GEMM core (R12-proven): C(128x128) = A @ W^T, K=1024, BK=32 ----------------
// Named accumulators; both-sides XOR swizzle (conflicts=0); single-barrier dbuf;
// XCD-chunked grid. LDS = one 32KB arena: As[2] at +0/+8K, Bs[2] at +16K/+24K;
// the same arena is reused by the R15 epilogue bounce after the mainloop.
#define GEMM_ACC_DECL                              \
  floatx4 c00 = {}, c01 = {}, c02 = {}, c03 = {};  \
  floatx4 c10 = {}, c11 = {}, c12 = {}, c13 = {};  \
  floatx4 c20 = {}, c21 = {}, c22 = {}, c23 = {};  \
  floatx4 c30 = {}, c31 = {}, c32 = {}, c33 = {};

#define AS_BASE(buf) ((char*)LDSBUF + (buf) * 8192)
#define BS_BASE(buf) ((char*)LDSBUF + 16384 + (buf) * 8192)

#define GEMM_STAGE(buf, kk)                                                    \
  gload_lds16(AS_BASE(buf) + (w * 64) * 16, asrc0 + (kk));                     \
  gload_lds16(BS_BASE(buf) + (w * 64) * 16, bsrc0 + (kk));                     \
  gload_lds16(AS_BASE(buf) + (w * 64 + 256) * 16, asrc1 + (kk));               \
  gload_lds16(BS_BASE(buf) + (w * 64 + 256) * 16, bsrc1 + (kk));

#define GEMM_MAINLOOP(Aptr, Bptr)                                              \
  const int c_0 = w * 64 + lane;                                               \
  const int row0_ = c_0 >> 2, seg0_ = (c_0 & 3) ^ ((row0_ >> 1) & 3);          \
  const int c_1 = c_0 + 256;                                                   \
  const int row1_ = c_1 >> 2, seg1_ = (c_1 & 3) ^ ((row1_ >> 1) & 3);          \
  const bf16* asrc0 = (Aptr) + (size_t)(bm + row0_) * D_MODEL + seg0_ * 8;     \
  const bf16* asrc1 = (Aptr) + (size_t)(bm + row1_) * D_MODEL + seg1_ * 8;     \
  const bf16* bsrc0 = (Bptr) + (size_t)(bn + row0_) * D_MODEL + seg0_ * 8;     \
  const bf16* bsrc1 = (Bptr) + (size_t)(bn + row1_) * D_MODEL + seg1_ * 8;     \
  const int gsw = (g ^ ((r >> 1) & 3)) * 8;                                    \
  GEMM_STAGE(0, 0)                                                             \
  __syncthreads();                                                             \
  int cub = 0;                                                                 \
  for (int kt = 0; kt < 32; ++kt) {                                            \
    if (kt + 1 < 32) { GEMM_STAGE(cub ^ 1, (kt + 1) * 32) }                    \
    const bf16* Abase = (const bf16*)AS_BASE(cub) + (wr * 64 + r) * 32 + gsw;  \
    const bf16* Bbase = (const bf16*)BS_BASE(cub) + (wc * 64 + r) * 32 + gsw;  \
    bf16x8 a0 = *(const bf16x8*)(Abase + 0 * 512);                             \
    bf16x8 a1 = *(const bf16x8*)(Abase + 1 * 512);                             \
    bf16x8 a2 = *(const bf16x8*)(Abase + 2 * 512);                             \
    bf16x8 a3 = *(const bf16x8*)(Abase + 3 * 512);                             \
    bf16x8 b0 = *(const bf16x8*)(Bbase + 0 * 512);                             \
    bf16x8 b1 = *(const bf16x8*)(Bbase + 1 * 512);                             \
    bf16x8 b2 = *(const bf16x8*)(Bbase + 2 * 512);                             \
    bf16x8 b3 = *(const bf16x8*)(Bbase + 3 * 512);                             \
    __builtin_amdgcn_s_setprio(1);                                             \
    c00 = mfma16(a0, b0, c00); c01 = mfma16(a0, b1, c01);                      \
    c02 = mfma16(a0, b2, c02); c03 = mfma16(a0, b3, c03);                      \
    c10 = mfma16(a1, b0, c10); c11 = mfma16(a1, b1, c11);                      \
    c12 = mfma16(a1, b2, c12); c13 = mfma16(a1, b3, c13);                      \
    c20 = mfma16(a2, b0, c20); c21 = mfma16(a2, b1, c21);                      \
    c22 = mfma16(a2, b2, c22); c23 = mfma16(a2, b3, c23);                      \
    c30 = mfma16(a3, b0, c30); c31 = mfma16(a3, b1, c31);                      \
    c32 = mfma16(a3, b2, c32); c33 = mfma16(a3, b3, c33);                      \
    __builtin_amdgcn_s_setprio(0);                                             \
    __syncthreads();                                                           \
    cub ^= 1;                                                                  \
  }

// ---------------- R15 epilogue: LDS-bounce for coalesced stores ----------------
// R12 evidence: gemm_out (same mainloop, plain row stores) runs ~637 TF vs
// gemm_qkv's 505 -> epilogue ~20us. V-transposed stores were 64 scattered 2B
// stores/thread (64 cachelines/instr); Q/K 32B chunks. Fix: bounce the RoPE'd
// tile through the freed 32KB LDS arena (pitch 272B = bank-rotating), re-read
// b128, store contiguous 16B (Q/K) / 64B-runs (V). Two 64-row passes.

// Q/K bounce write: rows = local s (0..63 within pass), cols = tile col c.
#define QKV_WRITE(mm, nn, CV)                                                  \
  _Pragma("unroll")                                                            \
  for (int reg = 0; reg < 4; ++reg) {                                          \
    const int srow = mm * 16 + g * 4 + reg;                                    \
    const int c = wc * 64 + nn * 16 + r;                                       \
    const int s_ = (bm + wr * 64 + srow) & (SEQ - 1);                          \
    const int d_ = c & 63;                                                     \
    float v = CV[reg];                                                         \
    float pp = __shfl_xor(v, 1);                                               \
    const float2 sc2 = ropetab[s_ * 32 + (d_ >> 1)];                           \
    float res = ((d_ & 1) == 0) ? (sc2.y * v - sc2.x * pp)                     \
                                : (sc2.x * pp + sc2.y * v);                    \
    if (z == 0) res *= 0.125f;                                                 \
    *(bf16*)((char*)LDSBUF + srow * 272 + c * 2) = (bf16)res;                  \
  }

// V bounce write: rows = local col c (0..63 within pass), cols = s (0..127).
#define V_WRITE(mm, nn, CV)                                                    \
  _Pragma("unroll")                                                            \
  for (int reg = 0; reg < 4; ++reg) {                                          \
    const int crow = nn * 16 + r;                                              \
    const int s_l = wr * 64 + mm * 16 + g * 4 + reg;                           \
    *(bf16*)((char*)LDSBUF + crow * 272 + s_l * 2) = (bf16)CV[reg];            \
  }

// grid (8, 64, 3) = 1536 blocks. XCD-chunked: l = (orig%8)*192 + orig/8.
// z=0: Q (RoPE, x0.125) -> [B,H,S,64]; z=1: K (RoPE); z=2: V -> [B,H,64,S].
__global__ __launch_bounds__(256, 3) void gemm_qkv(
    const bf16* __restrict__ A,
    const bf16* __restrict__ W0, const bf16* __restrict__ W1, const bf16* __restrict__ W2,
    bf16* __restrict__ Qd, bf16* __restrict__ Kd, bf16* __restrict__ Vd,
    const float2* __restrict__ ropetab) {
  __shared__ __align__(16) char LDSBUF[32768];
  const int orig = (int)(blockIdx.x + (blockIdx.y << 3) + (blockIdx.z << 9));
  const int l = (orig & 7) * 192 + (orig >> 3);
  const int z = l >> 9;
  const int bm = ((l >> 3) & 63) * 128, bn = (l & 7) * 128;
  const bf16* Bw = (z == 0) ? W0 : (z == 1) ? W1 : W2;
  const int tid = threadIdx.x, lane = tid & 63, w = tid >> 6;
  const int wr = w >> 1, wc = w & 1;
  const int r = lane & 15, g = lane >> 4;
  GEMM_ACC_DECL
  GEMM_MAINLOOP(A, Bw)
  // mainloop's final __syncthreads done: LDS arena free for the bounce.

  const int hbase = bn >> 6;
  if (z < 2) {
    bf16* dst0 = (z == 0) ? Qd : Kd;
#pragma unroll
    for (int p = 0; p < 2; ++p) {
      if (wr == p) {
        QKV_WRITE(0, 0, c00) QKV_WRITE(0, 1, c01) QKV_WRITE(0, 2, c02) QKV_WRITE(0, 3, c03)
        QKV_WRITE(1, 0, c10) QKV_WRITE(1, 1, c11) QKV_WRITE(1, 2, c12) QKV_WRITE(1, 3, c13)
        QKV_WRITE(2, 0, c20) QKV_WRITE(2, 1, c21) QKV_WRITE(2, 2, c22) QKV_WRITE(2, 3, c23)
        QKV_WRITE(3, 0, c30) QKV_WRITE(3, 1, c31) QKV_WRITE(3, 2, c32) QKV_WRITE(3, 3, c33)
      }
      __syncthreads();
      const int s_r = tid >> 2, quad = tid & 3;
      const int grow = bm + p * 64 + s_r;
      const int b_ = grow >> 11, s_ = grow & (SEQ - 1);
      const int h_ = hbase + (quad >> 1);
      bf16* dstp = dst0 + ((size_t)(b_ * NH + h_) * SEQ + s_) * DKH + (quad & 1) * 32;
#pragma unroll
      for (int j = 0; j < 4; ++j)
        *(float4*)(dstp + j * 8) =
            *(const float4*)((char*)LDSBUF + s_r * 272 + quad * 64 + j * 16);
      __syncthreads();
    }
  } else {
    const int b_ = bm >> 11, sbase = bm & (SEQ - 1);
#pragma unroll
    for (int p = 0; p < 2; ++p) {
      if (wc == p) {
        V_WRITE(0, 0, c00) V_WRITE(0, 1, c01) V_WRITE(0, 2, c02) V_WRITE(0, 3, c03)
        V_WRITE(1, 0, c10) V_WRITE(1, 1, c11) V_WRITE(1, 2, c12) V_WRITE(1, 3, c13)
        V_WRITE(2, 0, c20) V_WRITE(2, 1, c21) V_WRITE(2, 2, c22) V_WRITE(2, 3, c23)
        V_WRITE(3, 0, c30) V_WRITE(3, 1, c31) V_WRITE(3, 2, c32) V_WRITE(3, 3, c33)
      }
      __syncthreads();
      const int c_r = tid >> 2, quad = tid & 3;
      const int c = p * 64 + c_r;
      const int h_ = hbase + (c >> 6), d_ = c & 63;
      bf16* dstp = Vd + ((size_t)(b_ * NH + h_) * DKH + d_) * SEQ + sbase + quad * 32;
#pragma unroll
      for (int j = 0; j < 4; ++j)
        *(float4*)(dstp + j * 8) =
            *(const float4*)((char*)LDSBUF + c_r * 272 + quad * 64 + j * 16);
      __syncthreads();
    }
  }
}

// ---------------- output projection: d_out = AO @ Wo^T (fp32 row-major) ----------------
#define OUT_EPI(mm, nn, CV)                                                    \
  _Pragma("unroll")                                                            \
  for (int reg = 0; reg < 4; ++reg) {                                          \
    const int grow = bm + wr * 64 + mm * 16 + g * 4 + reg;                     \
    const int gcol = bn + wc * 64 + nn * 16 + r;                               \
    C[(size_t)grow * D_MODEL + gcol] = CV[reg];                                \
  }

// grid (8, 64) = 512 blocks; chunked swizzle with q = 64.
__global__ __launch_bounds__(256, 3) void gemm_out(const bf16* __restrict__ A,
                                                   const bf16* __restrict__ Bw,
                                                   float* __restrict__ C) {
  __shared__ __align__(16) char LDSBUF[32768];
  const int orig = (int)(blockIdx.x + (blockIdx.y << 3));
  const int l = (orig & 7) * 64 + (orig >> 3);
  const int bm = (l >> 3) * 128, bn = (l & 7) * 128;
  const int tid = threadIdx.x, lane = tid & 63, w = tid >> 6;
  const int wr = w >> 1, wc = w & 1;
  const int r = lane & 15, g = lane >> 4;
  GEMM_ACC_DECL
  GEMM_MAINLOOP(A, Bw)
  OUT_EPI(0, 0, c00) OUT_EPI(0, 1, c01) OUT_EPI(0, 2, c02) OUT_EPI(0, 3, c03)
  OUT_EPI(1, 0, c10) OUT_EPI(1, 1, c11) OUT_EPI(1, 2, c12) OUT_EPI(1, 3, c13)
  OUT_EPI(2, 0, c20) OUT_EPI(2, 1, c21) OUT_EPI(2, 2, c22) OUT_EPI(2, 3, c23)
  OUT_EPI(3, 0, c30) OUT_EPI(3, 1, c31) OUT_EPI(3, 2, c32) OUT_EPI(3, 3, c33)
}

// ---------------- causal flash attention, triangle-paired blocks (R12 state) ----------------
__global__ __launch_bounds__(256, 2) void attn128(const bf16* __restrict__ Q,
                                                  const bf16* __restrict__ Kk,
                                                  const bf16* __restrict__ Vt,
                                                  bf16* __restrict__ AO) {
  const int orig = (int)(blockIdx.x + (blockIdx.y << 3));
  const int l = (orig & 7) * 64 + (orig >> 3);
  const int bx = l & 7;
  const int bh = l >> 3;
  const int b = bh >> 4, h = bh & 15;
  const int tid = threadIdx.x, lane = tid & 63, w = tid >> 6;
  const int r = lane & 15, g = lane >> 4;

  const bf16* Qb = Q + (size_t)bh * SEQ * DKH;
  const bf16* Kb = Kk + (size_t)bh * SEQ * DKH;
  const bf16* Vb = Vt + (size_t)bh * DKH * SEQ;

  __shared__ bf16 Ks[2][64 * 64];  // [token][d], XOR-swizzled
  __shared__ bf16 Vs[2][64 * 64];  // [d][token], XOR-swizzled
  __shared__ bf16 Ps[4][32 * 64];  // per-wave P, XOR-swizzled

  // staging constants: linear LDS byte L -> pre-swizzled global source
  int ldsoff[2];
  const char* ksrc[2];
  const char* vsrc[2];
#pragma unroll
  for (int j = 0; j < 2; ++j) {
    const int L = (w * 64 + lane + 256 * j) * 16;
    const int S = L ^ (((L >> 7) & 7) << 4);
    ldsoff[j] = (w * 64 + 256 * j) * 16;
    ksrc[j] = (const char*)Kb + S;
    vsrc[j] = (const char*)Vb + (size_t)(S >> 7) * (SEQ * 2) + (S & 127);
  }

// K tile stride = 64 tok * 64 d * 2B = 8192 B; V tile stride = 64 tok * 2B = 128 B.
#define ATTN_STAGE(buf, tt)                                                   \
  _Pragma("unroll")                                                           \
  for (int j = 0; j < 2; ++j) {                                               \
    gload_lds16((char*)Ks[buf] + ldsoff[j], ksrc[j] + (size_t)(tt) * 8192);   \
    gload_lds16((char*)Vs[buf] + ldsoff[j], vsrc[j] + (size_t)(tt) * 128);    \
  }

// softmax tile body: p = exp2(fma(s, log2e, -12*log2e)); optional causal mask;
// accumulate l2; write bf16 p to swizzled Ps.
#define SM_TILE(MASKED)                                                        \
  _Pragma("unroll")                                                            \
  for (int m = 0; m < 2; ++m) {                                                \
    _Pragma("unroll")                                                          \
    for (int nf = 0; nf < 4; ++nf) {                                           \
      floatx4 p;                                                               \
      _Pragma("unroll")                                                        \
      for (int reg = 0; reg < 4; ++reg) {                                      \
        float pe = exp2f(fmaf(sc[m][nf][reg], 1.442695041f, -17.31234049f));   \
        if (MASKED && (t0 + nf * 16 + r > q0 + m * 16 + g * 4 + reg))          \
          pe = 0.f;                                                            \
        p[reg] = pe;                                                           \
      }                                                                        \
      l2[m] += p;                                                              \
      _Pragma("unroll")                                                        \
      for (int reg = 0; reg < 4; ++reg) {                                      \
        const int wl = m * 16 + g * 4 + reg;                                   \
        const int pb = (wl * 128 + (nf * 16 + r) * 2) ^ ((wl & 7) << 4);       \
        *(bf16*)((char*)Ps[w] + pb) = (bf16)p[reg];                            \
      }                                                                        \
    }                                                                          \
  }

  for (int half = 0; half < 2; ++half) {
    const int qt = half ? (15 - bx) : bx;
    const int q0 = qt * 128 + w * 32;

    // Q fragments: qf[m][ks], rows q0 + m*16 + r
    bf16x8 qf[2][2];
#pragma unroll
    for (int m = 0; m < 2; ++m)
#pragma unroll
      for (int ks = 0; ks < 2; ++ks)
        qf[m][ks] = *(const bf16x8*)(Qb + (size_t)(q0 + m * 16 + r) * DKH + ks * 32 + g * 8);

    floatx4 o[2][4] = {};
    floatx4 l2[2] = {};  // per-lane partial row-sums, reduced after the loop

    const int nt = 2 * qt + 2;
    ATTN_STAGE(0, 0)
    __syncthreads();
    int cu = 0;
    for (int t = 0; t < nt; ++t) {
      if (t + 1 < nt) ATTN_STAGE(cu ^ 1, t + 1)
      const int t0 = t * 64;

      // scores = Q @ K^T  (32 q-rows x 64 tokens), pre-scaled via Q
      floatx4 sc[2][4];
      __builtin_amdgcn_s_setprio(1);
#pragma unroll
      for (int nf = 0; nf < 4; ++nf) {
        const int row = nf * 16 + r;
        const int off0 = (row * 128 + g * 16) ^ ((row & 7) << 4);
        bf16x8 kf0 = *(const bf16x8*)((const char*)Ks[cu] + off0);
        bf16x8 kf1 = *(const bf16x8*)((const char*)Ks[cu] + (off0 ^ 64));
        sc[0][nf] = mfma16(qf[0][1], kf1, mfma16(qf[0][0], kf0, floatx4{0.f, 0.f, 0.f, 0.f}));
        sc[1][nf] = mfma16(qf[1][1], kf1, mfma16(qf[1][0], kf0, floatx4{0.f, 0.f, 0.f, 0.f}));
      }
      __builtin_amdgcn_s_setprio(0);

      const bool edge = (t0 + 63 > q0);  // wave-uniform branch
      if (edge) {
        SM_TILE(1)
      } else {
        SM_TILE(0)
      }
      // make this wave's P writes visible to its own ds_reads
      asm volatile("s_waitcnt lgkmcnt(0)" ::: "memory");

      // O += P @ V
      bf16x8 pf[2][2];
#pragma unroll
      for (int m = 0; m < 2; ++m)
#pragma unroll
        for (int ks = 0; ks < 2; ++ks) {
          const int prow = m * 16 + r;
          const int ab = (prow * 128 + ks * 64 + g * 16) ^ ((prow & 7) << 4);
          pf[m][ks] = *(const bf16x8*)((const char*)Ps[w] + ab);
        }
      __builtin_amdgcn_s_setprio(1);
#pragma unroll
      for (int nf = 0; nf < 4; ++nf) {
        const int vrow = nf * 16 + r;
        const int vb0 = (vrow * 128 + g * 16) ^ ((vrow & 7) << 4);
        bf16x8 vf0 = *(const bf16x8*)((const char*)Vs[cu] + vb0);
        bf16x8 vf1 = *(const bf16x8*)((const char*)Vs[cu] + (vb0 ^ 64));
#pragma unroll
        for (int m = 0; m < 2; ++m)
          o[m][nf] = mfma16(pf[m][1], vf1, mfma16(pf[m][0], vf0, o[m][nf]));
      }
      __builtin_amdgcn_s_setprio(0);
      __syncthreads();  // drains vmcnt (t+1 staged) + all reads of buffer cu done
      cu ^= 1;
    }

    // one-time row-sum reduction over the 16 r-lanes, then finalize
    float linv[2][4];
#pragma unroll
    for (int m = 0; m < 2; ++m)
#pragma unroll
      for (int reg = 0; reg < 4; ++reg) {
        float sum = l2[m][reg];
#pragma unroll
        for (int off = 1; off < 16; off <<= 1) sum += __shfl_xor(sum, off);
        linv[m][reg] = 1.f / sum;
      }

#pragma unroll
    for (int m = 0; m < 2; ++m)
#pragma unroll
      for (int nf = 0; nf < 4; ++nf)
#pragma unroll
        for (int reg = 0; reg < 4; ++reg) {
          const int s = q0 + m * 16 + g * 4 + reg;
          const int d = nf * 16 + r;
          const float val = o[m][nf][reg] * linv[m][reg];
          AO[((size_t)(b * SEQ + s)) * D_MODEL + h * DKH + d] = (bf16)val;
        }
  }
}

// ---------------- launcher ----------------
extern "C" void kernel_launch(void* const* d_in, const int* in_sizes, int n_in,
                              void* d_out, int out_size, void* d_ws, size_t ws_size,
                              hipStream_t stream) {
  const float* x = (const float*)d_in[0];
  const int* tokpos = (const int*)d_in[1];
  const float* Wq = (const float*)d_in[2];
  const float* Wk = (const float*)d_in[3];
  const float* Wv = (const float*)d_in[4];
  const float* Wo = (const float*)d_in[5];
  float* out = (float*)d_out;

  char* ws = (char*)d_ws;
  if (ws_size < (72ull << 20)) return;  // need 72 MiB scratch

  bf16* xb  = (bf16*)(ws);                     // 16 MiB [8192,1024]
  bf16* wb0 = (bf16*)(ws + (16ull << 20));     // 2 MiB each
  bf16* wb1 = (bf16*)(ws + (18ull << 20));
  bf16* wb2 = (bf16*)(ws + (20ull << 20));
  bf16* wb3 = (bf16*)(ws + (22ull << 20));
  bf16* Qb  = (bf16*)(ws + (24ull << 20));     // 16 MiB [B,H,S,64]
  bf16* Kb  = (bf16*)(ws + (40ull << 20));     // 16 MiB
  bf16* Vt  = (bf16*)(ws + (56ull << 20));     // 16 MiB [B,H,64,S]
  bf16* AO  = (bf16*)(ws);                     // reuse xb region (dead after QKV)
  // RoPE table lives in d_out's head (512 KB); consumed by gemm_qkv, then d_out
  // is fully overwritten by gemm_out afterwards (stream-ordered, deterministic).
  float2* ropetab = (float2*)d_out;

  rope_table<<<256, 256, 0, stream>>>(tokpos, ropetab);
  cvt_all<<<12288, 256, 0, stream>>>((const float4*)x, (const float4*)Wq,
                                     (const float4*)Wk, (const float4*)Wv,
                                     (const float4*)Wo, (bf16x4*)xb,
                                     (bf16x4*)wb0, (bf16x4*)wb1,
                                     (bf16x4*)wb2, (bf16x4*)wb3);

  gemm_qkv<<<dim3(8, 64, 3), 256, 0, stream>>>(xb, wb0, wb1, wb2, Qb, Kb, Vt, ropetab);
  attn128<<<dim3(8, 64), 256, 0, stream>>>(Qb, Kb, Vt, AO);
  gemm_out<<<dim3(8, 64), 256, 0, stream>>>(AO, wb3, out);
}